// Round 7
// baseline (55.151 us; speedup 1.0000x reference)
//
#include <hip/hip_runtime.h>
#include <cfloat>
#include <cmath>

#define F_   8
#define H_   24
#define W_   24
#define NTOK 4608
#define NSEQ 4609
#define MPAD 4736           // 37*128 = 74*64
#define DIM  512
#define QKVC 1536           // q | k | v
#define NNB  28
#define SCALEF 0.125f

typedef unsigned short ushort_t;
typedef __attribute__((ext_vector_type(8))) short short8v;
typedef __attribute__((ext_vector_type(8))) unsigned short ushort8v;
typedef __attribute__((ext_vector_type(4))) float floatx4;

typedef const __attribute__((address_space(1))) unsigned int guint_t;
typedef __attribute__((address_space(3))) unsigned int luint_t;

__device__ __forceinline__ float bf2f(unsigned short u) {
    return __uint_as_float(((unsigned)u) << 16);
}
__device__ __forceinline__ unsigned short f2bf(float f) {
    unsigned u = __float_as_uint(f);
    unsigned r = (u + 0x7FFFu + ((u >> 16) & 1u)) >> 16;
    return (unsigned short)r;
}
// pack two f32 -> u32 of 2 bf16 (truncation) via one v_perm_b32
__device__ __forceinline__ unsigned pk2(float a, float b) {
    return __builtin_amdgcn_perm(__float_as_uint(b), __float_as_uint(a), 0x07060302u);
}

// ---------------------------------------------------------------------------
// Weight conversion only (x conversion is fused into gemm_qkv staging):
//  blocks [0,192):   [w_q | w_kv] -> wcatT (bf16, [1536][512])
//  blocks [192,256): w_out -> woutT (bf16, [512][512])
// 64x64 LDS-tile transpose; coalesced f32 reads, coalesced ushort8 writes.
// ---------------------------------------------------------------------------
#define CONV_BLOCKS 256

__global__ __launch_bounds__(256) void conv_k(
    const float* __restrict__ wq, const float* __restrict__ wkv,
    const float* __restrict__ wout,
    ushort_t* __restrict__ wcatT, ushort_t* __restrict__ woutT)
{
    const int blk2 = blockIdx.x, tid = threadIdx.x;
    __shared__ ushort_t tile[64][72];

    const float* src; int ld, cb; ushort_t* dst; int k0;
    if (blk2 < 192) {
        int nt = blk2 >> 3, kt = blk2 & 7;
        int n0 = nt * 64;
        if (n0 < 512) { src = wq;  ld = 512;  cb = n0; }
        else          { src = wkv; ld = 1024; cb = n0 - 512; }
        dst = wcatT + (size_t)n0 * 512;
        k0 = kt * 64;
    } else {
        int b3 = blk2 - 192;
        int nt = b3 >> 3, kt = b3 & 7;
        src = wout; ld = 512; cb = nt * 64;
        dst = woutT + (size_t)(nt * 64) * 512;
        k0 = kt * 64;
    }

    {
        int r = tid >> 4, c4 = (tid & 15) * 4;
        #pragma unroll
        for (int p = 0; p < 4; ++p) {
            int rr = r + p * 16;
            float4 v = *reinterpret_cast<const float4*>(&src[(size_t)(k0 + rr) * ld + cb + c4]);
            tile[c4 + 0][rr] = f2bf(v.x);
            tile[c4 + 1][rr] = f2bf(v.y);
            tile[c4 + 2][rr] = f2bf(v.z);
            tile[c4 + 3][rr] = f2bf(v.w);
        }
    }
    __syncthreads();
    {
        int nl = tid >> 3, ks = (tid & 7) * 8;
        #pragma unroll
        for (int rep = 0; rep < 2; ++rep) {
            int nn = nl + rep * 32;
            ushort8v vv = *reinterpret_cast<const ushort8v*>(&tile[nn][ks]);
            *reinterpret_cast<ushort8v*>(&dst[(size_t)nn * 512 + k0 + ks]) = vv;
        }
    }
}

// ---------------------------------------------------------------------------
// bf16 MFMA GEMM, single-buffered: stage -> barrier -> compute -> barrier.
// BM=64 x 128 tile, BK=64, 4 waves, 16x16x32 MFMA, XOR slot swizzle,
// bijective XCD-chunked block swizzle, __launch_bounds__(256,4).
// F32A: A is f32 [NSEQ][512]; reg-staged with v_perm bf16-truncation pack
//       (fused x->bf16 conversion; rows >= NSEQ are zero).
// else: A is bf16, staged via async global_load_lds.
// B is always bf16 [N][512], async global_load_lds (issued first).
// ---------------------------------------------------------------------------
template<int BM, bool F32A, bool F32OUT>
__global__ __launch_bounds__(256, 4) void gemm_k(
    const void* __restrict__ Av,
    const ushort_t* __restrict__ BT,   // [N][512] bf16
    const float* __restrict__ bias,
    void* __restrict__ Cv, int ldc)
{
    __shared__ ushort_t sA[BM * 64];
    __shared__ ushort_t sB[128 * 64];
    const int tid = threadIdx.x;

    const int nwg = gridDim.x * gridDim.y;
    const int orig = blockIdx.y * gridDim.x + blockIdx.x;
    const int xcd = orig & 7;
    const int qq = nwg >> 3, rr8 = nwg & 7;
    const int wg = (xcd < rr8 ? xcd * (qq + 1) : rr8 * (qq + 1) + (xcd - rr8) * qq)
                   + (orig >> 3);
    const int row0 = (wg / gridDim.x) * BM;
    const int col0 = (wg % gridDim.x) * 128;

    const int wid = tid >> 6, lane = tid & 63;
    const int wr = wid >> 1, wc = wid & 1;
    const int l15 = lane & 15, kp = lane >> 4;
    constexpr int MR = BM / 32;        // m-fragments per wave

    floatx4 acc[MR][4];
    #pragma unroll
    for (int m = 0; m < MR; ++m)
        #pragma unroll
        for (int n = 0; n < 4; ++n)
            acc[m][n] = (floatx4){0.f, 0.f, 0.f, 0.f};

    const ushort_t* Ab = (const ushort_t*)Av;
    const float*    Af = (const float*)Av;
    const ushort_t* Bbase = BT + (size_t)col0 * 512;

    for (int kt = 0; kt < 8; ++kt) {
        const int k0 = kt * 64;
        // B first: async global->LDS, in flight during A reg-staging
        #pragma unroll
        for (int rnd = 0; rnd < 4; ++rnd) {
            int r = rnd * 32 + (tid >> 3);
            int gs = (tid & 7) ^ (r & 7);
            __builtin_amdgcn_global_load_lds(
                (guint_t*)(Bbase + (size_t)r * 512 + k0 + gs * 8),
                (luint_t*)(sB + r * 64 + (tid & 7) * 8), 16, 0, 0);
        }
        if constexpr (F32A) {
            static_assert(BM == 64, "F32A staging assumes BM==64");
            int r = tid >> 2;                   // 0..63
            int kq = (tid & 3) << 4;            // 0,16,32,48
            float4 f0 = make_float4(0.f,0.f,0.f,0.f), f1 = f0, f2 = f0, f3 = f0;
            if (row0 + r < NSEQ) {
                const float* sp = Af + (size_t)(row0 + r) * 512 + k0 + kq;
                f0 = *(const float4*)(sp + 0);
                f1 = *(const float4*)(sp + 4);
                f2 = *(const float4*)(sp + 8);
                f3 = *(const float4*)(sp + 12);
            }
            uint4 lo, hi;
            lo.x = pk2(f0.x, f0.y); lo.y = pk2(f0.z, f0.w);
            lo.z = pk2(f1.x, f1.y); lo.w = pk2(f1.z, f1.w);
            hi.x = pk2(f2.x, f2.y); hi.y = pk2(f2.z, f2.w);
            hi.z = pk2(f3.x, f3.y); hi.w = pk2(f3.z, f3.w);
            int slot0 = kq >> 3;                // 0,2,4,6
            *(uint4*)&sA[r * 64 + ((slot0       ^ (r & 7)) << 3)] = lo;
            *(uint4*)&sA[r * 64 + (((slot0 | 1) ^ (r & 7)) << 3)] = hi;
        } else {
            #pragma unroll
            for (int rnd = 0; rnd < BM / 32; ++rnd) {
                int r = rnd * 32 + (tid >> 3);
                int gs = (tid & 7) ^ (r & 7);
                __builtin_amdgcn_global_load_lds(
                    (guint_t*)(Ab + (size_t)(row0 + r) * 512 + k0 + gs * 8),
                    (luint_t*)(sA + r * 64 + (tid & 7) * 8), 16, 0, 0);
            }
        }
        __syncthreads();

        #pragma unroll
        for (int kk = 0; kk < 2; ++kk) {
            short8v af[MR], bfr[4];
            #pragma unroll
            for (int m = 0; m < MR; ++m) {
                int r = wr * (BM / 2) + m * 16 + l15;
                int slot = kk * 4 + kp;
                af[m] = *(const short8v*)&sA[r * 64 + ((slot ^ (r & 7)) << 3)];
            }
            #pragma unroll
            for (int n = 0; n < 4; ++n) {
                int r = wc * 64 + n * 16 + l15;
                int slot = kk * 4 + kp;
                bfr[n] = *(const short8v*)&sB[r * 64 + ((slot ^ (r & 7)) << 3)];
            }
            #pragma unroll
            for (int m = 0; m < MR; ++m)
                #pragma unroll
                for (int n = 0; n < 4; ++n)
                    acc[m][n] = __builtin_amdgcn_mfma_f32_16x16x32_bf16(
                        af[m], bfr[n], acc[m][n], 0, 0, 0);
        }
        __syncthreads();
    }

    if (!F32OUT) {
        ushort_t* C = (ushort_t*)Cv;
        #pragma unroll
        for (int m = 0; m < MR; ++m) {
            int rb = row0 + wr * (BM / 2) + m * 16 + kp * 4;
            #pragma unroll
            for (int n = 0; n < 4; ++n) {
                int col = col0 + wc * 64 + n * 16 + l15;
                #pragma unroll
                for (int q = 0; q < 4; ++q)
                    C[(size_t)(rb + q) * ldc + col] = f2bf(acc[m][n][q]);
            }
        }
    } else {
        float* C = (float*)Cv;
        #pragma unroll
        for (int m = 0; m < MR; ++m) {
            int rb = row0 + wr * (BM / 2) + m * 16 + kp * 4;
            #pragma unroll
            for (int n = 0; n < 4; ++n) {
                int col = col0 + wc * 64 + n * 16 + l15;
                float bv = bias[col];
                #pragma unroll
                for (int q = 0; q < 4; ++q)
                    if (rb + q < NSEQ)
                        C[(size_t)(rb + q) * ldc + col] = acc[m][n][q] + bv;
            }
        }
    }
}

// ---------------------------------------------------------------------------
// Attention, wave-per-token, XCD-chunked swizzle. New this round:
//  - masked neighbors (causal/OOB, ~half of the 27) SKIP their K and V row
//    loads entirely (rows[j] is wave-uniform -> execz skip, no divergence)
//  - PV shfl broadcasts hoisted out of the V-load loop (no serial
//    shfl->load->fma chain)
// ---------------------------------------------------------------------------
__global__ __launch_bounds__(256) void attn_k(
    const ushort_t* __restrict__ qkv,
    const float* __restrict__ wtalk,
    ushort_t* __restrict__ outh)
{
    const int lane = threadIdx.x & 63;
    const int bid0 = blockIdx.x;                            // 1152 = 8*144
    const int bswz = (bid0 & 7) * (gridDim.x >> 3) + (bid0 >> 3);
    const int i = bswz * 4 + (threadIdx.x >> 6);
    const int h = lane >> 3, s = lane & 7;

    const int t = i / (H_ * W_), rem = i % (H_ * W_);
    const int yy = rem / W_, xx = rem % W_;

    int rowj = -1;
    if (lane == 0) rowj = 0;
    else if (lane < NNB) {
        int e = lane - 1;
        int dt = e / 9 - 1, dy = (e / 3) % 3 - 1, dx = e % 3 - 1;
        int nt = t + dt, ny = yy + dy, nx = xx + dx;
        bool valid = ((unsigned)nt < (unsigned)F_) && ((unsigned)ny < (unsigned)H_) &&
                     ((unsigned)nx < (unsigned)W_);
        int u = (nt * H_ + ny) * W_ + nx;
        rowj = (valid && u <= i) ? (u + 1) : -1;
    }

    int rows[NNB];
    #pragma unroll
    for (int j = 0; j < NNB; ++j) rows[j] = __shfl(rowj, j, 64);

    float qf[8];
    {
        ushort8v qv = *(const ushort8v*)&qkv[(size_t)(i + 1) * QKVC + lane * 8];
        #pragma unroll
        for (int e = 0; e < 8; ++e) qf[e] = bf2f(qv[e]);
    }

    // partial dots; masked rows skipped (wave-uniform branch)
    float ps[NNB];
    #pragma unroll
    for (int j = 0; j < NNB; ++j) {
        float a = 0.f;
        if (rows[j] >= 0) {
            ushort8v kv = *(const ushort8v*)&qkv[(size_t)rows[j] * QKVC + 512 + lane * 8];
            #pragma unroll
            for (int e = 0; e < 8; ++e) a += qf[e] * bf2f(kv[e]);
        }
        ps[j] = a;
    }

    float v1[14];
    {
        bool hi = (s & 1) != 0;
        #pragma unroll
        for (int m = 0; m < 14; ++m) {
            float keep = hi ? ps[2 * m + 1] : ps[2 * m];
            float oth  = hi ? ps[2 * m]     : ps[2 * m + 1];
            v1[m] = keep + __shfl_xor(oth, 1, 64);
        }
    }
    float v2[8];
    {
        bool hi = (s & 2) != 0;
        #pragma unroll
        for (int m = 0; m < 7; ++m) {
            float keep = hi ? v1[2 * m + 1] : v1[2 * m];
            float oth  = hi ? v1[2 * m]     : v1[2 * m + 1];
            v2[m] = keep + __shfl_xor(oth, 2, 64);
        }
        v2[7] = 0.f;
    }
    float simk[4];
    {
        bool hi = (s & 4) != 0;
        #pragma unroll
        for (int k = 0; k < 4; ++k) {
            float keep = hi ? v2[2 * k + 1] : v2[2 * k];
            float oth  = hi ? v2[2 * k]     : v2[2 * k + 1];
            simk[k] = keep + __shfl_xor(oth, 4, 64);
        }
    }
    #pragma unroll
    for (int k = 0; k < 4; ++k) {
        int j = s + 8 * k;
        int rj = __shfl(rowj, j, 64);
        simk[k] = (rj >= 0) ? simk[k] * SCALEF : -FLT_MAX;
    }

    float mx = fmaxf(fmaxf(simk[0], simk[1]), fmaxf(simk[2], simk[3]));
    mx = fmaxf(mx, __shfl_xor(mx, 1, 64));
    mx = fmaxf(mx, __shfl_xor(mx, 2, 64));
    mx = fmaxf(mx, __shfl_xor(mx, 4, 64));
    float att[4];
    float S = 0.f;
    #pragma unroll
    for (int k = 0; k < 4; ++k) { att[k] = __expf(simk[k] - mx); S += att[k]; }
    S += __shfl_xor(S, 1, 64);
    S += __shfl_xor(S, 2, 64);
    S += __shfl_xor(S, 4, 64);
    float inv = 1.f / S;
    #pragma unroll
    for (int k = 0; k < 4; ++k) att[k] *= inv;

    float wtg[8];
    #pragma unroll
    for (int hh = 0; hh < 8; ++hh) wtg[hh] = wtalk[h * 8 + hh];
    float pk[4];
    #pragma unroll
    for (int k = 0; k < 4; ++k) {
        float acc = 0.f;
        #pragma unroll
        for (int hh = 0; hh < 8; ++hh)
            acc += wtg[hh] * __shfl(att[k], hh * 8 + s, 64);
        pk[k] = acc;
    }

    // hoisted PV broadcasts (independent shfls, latency overlapped)
    float pj[NNB];
    #pragma unroll
    for (int j = 0; j < NNB; ++j)
        pj[j] = __shfl(pk[j >> 3], h * 8 + (j & 7), 64);

    float o[8];
    #pragma unroll
    for (int e = 0; e < 8; ++e) o[e] = 0.f;
    #pragma unroll
    for (int j = 0; j < NNB; ++j) {
        if (rows[j] >= 0) {
            ushort8v vv = *(const ushort8v*)&qkv[(size_t)rows[j] * QKVC + 1024 + lane * 8];
            #pragma unroll
            for (int e = 0; e < 8; ++e) o[e] += pj[j] * bf2f(vv[e]);
        }
    }

    ushort8v ov;
    #pragma unroll
    for (int e = 0; e < 8; ++e) ov[e] = f2bf(o[e]);
    *(ushort8v*)&outh[(size_t)(i + 1) * DIM + lane * 8] = ov;

    if (i == 0) {
        ushort8v bv = *(const ushort8v*)&qkv[1024 + lane * 8];
        *(ushort8v*)&outh[lane * 8] = bv;
    }
}

extern "C" void kernel_launch(void* const* d_in, const int* in_sizes, int n_in,
                              void* d_out, int out_size, void* d_ws, size_t ws_size,
                              hipStream_t stream) {
    const float* x     = (const float*)d_in[0];
    const float* wq    = (const float*)d_in[1];
    const float* wkv   = (const float*)d_in[2];
    const float* wtalk = (const float*)d_in[3];
    const float* wout  = (const float*)d_in[4];
    const float* bout  = (const float*)d_in[5];
    float* out = (float*)d_out;

    ushort_t* wcatT = (ushort_t*)d_ws;                    // 1536*512 bf16
    ushort_t* woutT = wcatT + (size_t)QKVC * 512;         // 512*512
    ushort_t* qkv   = woutT + (size_t)512 * 512;          // MPAD*1536
    ushort_t* outh  = qkv   + (size_t)MPAD * QKVC;        // MPAD*512

    dim3 blk(256);
    conv_k<<<CONV_BLOCKS, blk, 0, stream>>>(wq, wkv, wout, wcatT, woutT);
    gemm_k<64, true, false><<<dim3(12, 74), blk, 0, stream>>>(x, wcatT, nullptr, qkv, QKVC);
    attn_k<<<dim3(NTOK / 4), blk, 0, stream>>>(qkv, wtalk, outh);
    gemm_k<64, false, true><<<dim3(4, 74), blk, 0, stream>>>(outh, woutT, bout, out, DIM);
}